// Round 6
// baseline (180.982 us; speedup 1.0000x reference)
//
#include <hip/hip_runtime.h>
#include <hip/hip_bf16.h>
#include <math.h>

#define B_   128
#define Qn   30
#define Dn   200
#define En   300

typedef __attribute__((ext_vector_type(8))) short short8;
typedef __attribute__((ext_vector_type(4))) float floatx4;
typedef unsigned int u32;
typedef unsigned short u16;

static __device__ __forceinline__ u16 f2b(float x) {   // fp32 -> bf16 RNE
    union { float f; u32 u; } v; v.f = x;
    u32 r = v.u + 0x7FFFu + ((v.u >> 16) & 1u);
    return (u16)(r >> 16);
}
static __device__ __forceinline__ float bits2f(u32 u) {
    union { u32 u2; float f; } v; v.u2 = u; return v.f;
}

// ---------------------------------------------------------------------------
// prep: weight permute (bx<8) + pkg zero-init (bx>=8; avoids a memset API
// call inside graph capture). Wt3 ks-major layout as before.
// ---------------------------------------------------------------------------
__global__ void prep_kernel(
    const float* __restrict__ w1, const float* __restrict__ w2, const float* __restrict__ w3,
    u16* __restrict__ Wt3, float* __restrict__ pkg)
{
    if (blockIdx.x >= 8) {                      // zero pkg[442368]
        int zi = ((blockIdx.x - 8)*128 + blockIdx.y)*256 + threadIdx.x;
        if (zi < 442368) pkg[zi] = 0.f;
        int zi2 = zi + 229376;
        if (zi2 < 442368) pkg[zi2] = 0.f;
        return;
    }
    int p = (blockIdx.x*128 + blockIdx.y)*256 + threadIdx.x;
    if (p >= 245760) return;
    int ks = p / 24576;
    int r  = p - ks*24576;
    int g, rr;
    if (r < 4096)        { g = 0; rr = r;         }
    else if (r < 12288)  { g = 1; rr = r - 4096;  }
    else                 { g = 2; rr = r - 12288; }
    int j  = rr >> 12;
    int r2 = rr & 4095;
    int nt  = r2 >> 9;
    int q4  = (r2 >> 7) & 3;
    int c16 = (r2 >> 3) & 15;
    int k8  = r2 & 7;
    int ch = nt*16 + c16;
    int e  = ks*32 + q4*8 + k8;
    float v = 0.f;
    if (e < En) {
        if (g == 0)      v = w1[ch*En + e];
        else if (g == 1) v = w2[(ch*En + e)*2 + j];
        else             v = w3[(ch*En + e)*3 + j];
    }
    Wt3[p] = f2b(v);
}

// ---------------------------------------------------------------------------
// Fused conv (R4 structure, UNCHANGED this round).
// ---------------------------------------------------------------------------
__global__ __launch_bounds__(512, 4) void conv_kernel(
    const int* __restrict__ qtok, const int* __restrict__ dtok,
    const float* __restrict__ emb,
    const u16* __restrict__ Wt3,
    const float* __restrict__ b1, const float* __restrict__ b2, const float* __restrict__ b3,
    u16* __restrict__ qg, u16* __restrict__ dg,
    float* __restrict__ invnq, float* __restrict__ invnd)
{
    __shared__ __align__(16) char smem[43560];   // As [66][656] + toks[66]
    char* As  = smem;
    int*  toks = (int*)(smem + 43296);

    const int tile = blockIdx.x;
    const int tid = threadIdx.x;
    const int wv = tid >> 6, lane = tid & 63;
    const int l15 = lane & 15, qd4 = lane >> 4;
    const int mh = wv >> 2, nh = wv & 3;
    const int gR0 = tile*64;

    if (tid < 66) {
        int gr = gR0 + tid;
        int t = -1;
        if (gr < 32768) {
            int b = gr >> 8, pos = gr & 255;
            if (pos < Dn) t = dtok[b*Dn + pos];
            else if (pos >= 208 && pos < 238) t = qtok[b*Qn + (pos - 208)];
        }
        toks[tid] = t;
    }
    __syncthreads();

    #pragma unroll
    for (int i = 0; i < 6; ++i) {
        int idx = tid + i*512;
        if (idx < 2640) {
            int r = idx / 40, c4 = idx - r*40;
            int t = toks[r];
            u16 o0=0,o1=0,o2=0,o3=0;
            if (t >= 0) {
                float4 v = *(const float4*)(emb + t*En + c4*4);
                o0=f2b(v.x); o1=f2b(v.y); o2=f2b(v.z); o3=f2b(v.w);
            }
            u16* pdst = (u16*)(As + r*656 + c4*8);
            pdst[0]=o0; pdst[1]=o1; pdst[2]=o2; pdst[3]=o3;
        }
    }

    float bias[3][2];
    #pragma unroll
    for (int nt = 0; nt < 2; ++nt) {
        int ch = nh*32 + nt*16 + l15;
        bias[0][nt] = b1[ch];
        bias[1][nt] = b2[ch];
        bias[2][nt] = b3[ch];
    }

    floatx4 acc[3][2][2];
    #pragma unroll
    for (int g = 0; g < 3; ++g)
        #pragma unroll
        for (int mt = 0; mt < 2; ++mt)
            #pragma unroll
            for (int nt = 0; nt < 2; ++nt)
                acc[g][mt][nt] = (floatx4){0.f,0.f,0.f,0.f};

    __syncthreads();                        // A K-lo ready

    float4 hf[6];
    #pragma unroll
    for (int i = 0; i < 6; ++i) {
        int idx = tid + i*512;
        const float* p = emb;               // safe dummy
        if (idx < 2640) {
            int r = idx / 40, c = idx - r*40;
            int t = toks[r];
            if (t >= 0 && c < 35) p = emb + t*En + (40 + c)*4;
        }
        hf[i] = *(const float4*)p;
    }

    #pragma unroll 1
    for (int ks = 0; ks < 5; ++ks) {
        short8 af[2][3];
        #pragma unroll
        for (int mt = 0; mt < 2; ++mt)
            #pragma unroll
            for (int j = 0; j < 3; ++j)
                af[mt][j] = *(const short8*)(As + (mh*32 + mt*16 + l15 + j)*656 + ks*64 + qd4*16);
        const u16* Wks = Wt3 + ks*24576;
        #pragma unroll
        for (int g = 0; g < 3; ++g) {
            const int cbW = (g == 0) ? 0 : (g == 1) ? 4096 : 12288;
            #pragma unroll
            for (int j = 0; j <= g; ++j) {
                const u16* bb = Wks + cbW + (j*8 + nh*2)*512 + lane*8;
                short8 w0  = *(const short8*)(bb);
                short8 w1v = *(const short8*)(bb + 512);
                #pragma unroll
                for (int mt = 0; mt < 2; ++mt) {
                    acc[g][mt][0] = __builtin_amdgcn_mfma_f32_16x16x32_bf16(
                        af[mt][j], w0,  acc[g][mt][0], 0, 0, 0);
                    acc[g][mt][1] = __builtin_amdgcn_mfma_f32_16x16x32_bf16(
                        af[mt][j], w1v, acc[g][mt][1], 0, 0, 0);
                }
            }
        }
    }

    #pragma unroll
    for (int i = 0; i < 6; ++i) {
        int idx = tid + i*512;
        if (idx < 2640) {
            int r = idx / 40, c = idx - r*40;
            int t = toks[r];
            bool ok = (t >= 0) && (c < 35);
            u16 o0=0,o1=0,o2=0,o3=0;
            if (ok) { o0=f2b(hf[i].x); o1=f2b(hf[i].y); o2=f2b(hf[i].z); o3=f2b(hf[i].w); }
            u16* pdst = (u16*)(As + r*656 + (40 + c)*8);
            pdst[0]=o0; pdst[1]=o1; pdst[2]=o2; pdst[3]=o3;
        }
    }
    __syncthreads();                        // K-hi ready

    #pragma unroll 1
    for (int ks = 5; ks < 10; ++ks) {
        short8 af[2][3];
        #pragma unroll
        for (int mt = 0; mt < 2; ++mt)
            #pragma unroll
            for (int j = 0; j < 3; ++j)
                af[mt][j] = *(const short8*)(As + (mh*32 + mt*16 + l15 + j)*656 + ks*64 + qd4*16);
        const u16* Wks = Wt3 + ks*24576;
        #pragma unroll
        for (int g = 0; g < 3; ++g) {
            const int cbW = (g == 0) ? 0 : (g == 1) ? 4096 : 12288;
            #pragma unroll
            for (int j = 0; j <= g; ++j) {
                const u16* bb = Wks + cbW + (j*8 + nh*2)*512 + lane*8;
                short8 w0  = *(const short8*)(bb);
                short8 w1v = *(const short8*)(bb + 512);
                #pragma unroll
                for (int mt = 0; mt < 2; ++mt) {
                    acc[g][mt][0] = __builtin_amdgcn_mfma_f32_16x16x32_bf16(
                        af[mt][j], w0,  acc[g][mt][0], 0, 0, 0);
                    acc[g][mt][1] = __builtin_amdgcn_mfma_f32_16x16x32_bf16(
                        af[mt][j], w1v, acc[g][mt][1], 0, 0, 0);
                }
            }
        }
    }

    u16* Gs = (u16*)smem;                   // [64][136]
    #pragma unroll
    for (int g = 0; g < 3; ++g) {
        __syncthreads();
        #pragma unroll
        for (int mt = 0; mt < 2; ++mt)
            #pragma unroll
            for (int nt = 0; nt < 2; ++nt) {
                int ch = nh*32 + nt*16 + l15;
                #pragma unroll
                for (int i = 0; i < 4; ++i) {
                    int row = mh*32 + mt*16 + qd4*4 + i;
                    Gs[row*136 + ch] = f2b(fmaxf(acc[g][mt][nt][i] + bias[g][nt], 0.f));
                }
            }
        __syncthreads();

        {
            int r = tid >> 3, pp = tid & 7;
            const char* rp = (const char*)Gs + r*272 + pp*32;
            float ssum = 0.f;
            #pragma unroll
            for (int t2 = 0; t2 < 2; ++t2) {
                uint4 u = *(const uint4*)(rp + t2*16);
                float x;
                x = bits2f(u.x << 16); ssum += x*x;  x = bits2f(u.x & 0xffff0000u); ssum += x*x;
                x = bits2f(u.y << 16); ssum += x*x;  x = bits2f(u.y & 0xffff0000u); ssum += x*x;
                x = bits2f(u.z << 16); ssum += x*x;  x = bits2f(u.z & 0xffff0000u); ssum += x*x;
                x = bits2f(u.w << 16); ssum += x*x;  x = bits2f(u.w & 0xffff0000u); ssum += x*x;
            }
            ssum += __shfl_xor(ssum, 1);
            ssum += __shfl_xor(ssum, 2);
            ssum += __shfl_xor(ssum, 4);
            if (pp == 0) {
                float inv = 1.f / (sqrtf(ssum) + 1e-13f);
                int gr = gR0 + r;
                int b = gr >> 8, pos = gr & 255;
                if (pos < 208)      invnd[(g*B_ + b)*208 + pos] = inv;
                else if (pos < 238) invnq[(g*B_ + b)*32 + (pos - 208)] = inv;
            }
        }
        #pragma unroll
        for (int i = 0; i < 2; ++i) {
            int idx = tid + i*512;
            int r = idx >> 4, c16 = idx & 15;
            uint4 v = *(const uint4*)((const char*)Gs + r*272 + c16*16);
            int gr = gR0 + r;
            int b = gr >> 8, pos = gr & 255;
            if (pos < 208)      *(uint4*)(dg + ((g*B_ + b)*208 + pos)*128 + c16*8) = v;
            else if (pos < 238) *(uint4*)(qg + ((g*B_ + b)*32 + (pos - 208))*128 + c16*8) = v;
        }
    }
}

// ---------------------------------------------------------------------------
// Pool, R6: grid (3 dj, 128 b, 4 th) = 1536 blocks (4x TLP vs R3's 384).
// th splits the 13 d-tiles {4,3,3,3}; each block stages only its d-rows
// (<=17.4 KB LDS), runs the R3 register-friendly body (qi-outer, hoisted qf,
// one t-tile per wave), reduces into LDS pk, then flushes the block partial
// to global pkg with ~5 atomic instructions per thread. Log tail + dense
// moved to final_kernel. launch_bounds(256,2) keeps the 256-VGPR budget
// (R4 lesson: tighter caps spill to scratch invisibly).
// ---------------------------------------------------------------------------
__global__ __launch_bounds__(256, 2) void pool_kernel(
    const u16* __restrict__ qg, const u16* __restrict__ dg,
    const float* __restrict__ invnq, const float* __restrict__ invnd,
    const int* __restrict__ qtok, const int* __restrict__ dtok,
    float* __restrict__ pkg)
{
    __shared__ __align__(16) u16 dsb[64*136];      // 17408 B
    __shared__ float pk[96*12];                    // 4608 B
    __shared__ float invqA[96];
    __shared__ __align__(16) float invd[64];

    const int tid = threadIdx.x;
    const int b = blockIdx.y, dj = blockIdx.x, th = blockIdx.z;
    const int wv = tid >> 6, lane = tid & 63;
    const int l15 = lane & 15, qd4 = lane >> 4;

    const int ts = (th == 0) ? 0 : (th == 1) ? 4 : (th == 2) ? 7 : 10;
    const int te = (th == 0) ? 4 : (th == 1) ? 7 : (th == 2) ? 10 : 13;
    const int r0 = ts*16, nrows = (te - ts)*16;

    for (int idx = tid; idx < nrows*16; idx += 256) {
        int r = idx >> 4, ch = idx & 15;
        int gr = r0 + r;
        uint4 v = make_uint4(0u,0u,0u,0u);
        if (gr < Dn) v = *(const uint4*)(dg + ((dj*B_ + b)*208 + gr)*128 + ch*8);
        *(uint4*)((char*)dsb + r*272 + ch*16) = v;
    }
    if (tid < nrows) {
        int gr = r0 + tid;
        float v = invnd[(dj*B_ + b)*208 + gr];
        bool ok = (gr < Dn) && (dtok[b*Dn + gr] > 0);
        invd[tid] = ok ? v : (-fabsf(v) - 1.0f);   // strictly negative if masked
    }
    if (tid < 96) {
        int qi = tid >> 5, qr = tid & 31;
        float v = invnq[(qi*B_ + b)*32 + qr];
        bool ok = (qr < Qn) && (qtok[b*Qn + qr] > 0);
        invqA[tid] = ok ? v : 0.f;
    }
    for (int i = tid; i < 96*12; i += 256) pk[i] = 0.f;
    __syncthreads();

    // chain constants C_k = exp(10*(mu_k + mu_{k+1})), mu: 0.9,0.7,...,-0.9
    const float CkR[9] = {8886110.5f, 162754.79f, 2980.958f, 54.598150f, 1.0f,
                          0.018315639f, 3.3546263e-4f, 6.1442124e-6f, 1.1253517e-7f};

    const int t = ts + wv;                          // one tile per wave
    const bool active = (t < te);
    const int tl = t - ts;                          // local tile idx

    for (int qi = 0; qi < 3; ++qi) {
        short8 qf[2][4];
        float vq[2];
        #pragma unroll
        for (int qt = 0; qt < 2; ++qt) {
            vq[qt] = invqA[qi*32 + qt*16 + l15];
            #pragma unroll
            for (int ks = 0; ks < 4; ++ks)
                qf[qt][ks] = *(const short8*)(qg + ((qi*B_ + b)*32 + qt*16 + l15)*128 + ks*32 + qd4*8);
        }
        float pkl[2][11];
        #pragma unroll
        for (int qt = 0; qt < 2; ++qt)
            #pragma unroll
            for (int k = 0; k < 11; ++k) pkl[qt][k] = 0.f;

        if (active) {
            short8 af[4];
            #pragma unroll
            for (int ks = 0; ks < 4; ++ks)
                af[ks] = *(const short8*)((const char*)dsb + (tl*16 + l15)*272 + ks*64 + qd4*16);
            floatx4 acc[2];
            acc[0] = (floatx4){0.f,0.f,0.f,0.f};
            acc[1] = (floatx4){0.f,0.f,0.f,0.f};
            #pragma unroll
            for (int ks = 0; ks < 4; ++ks)
                #pragma unroll
                for (int qt = 0; qt < 2; ++qt)
                    acc[qt] = __builtin_amdgcn_mfma_f32_16x16x32_bf16(af[ks], qf[qt][ks], acc[qt], 0, 0, 0);
            floatx4 iv4 = *(const floatx4*)(invd + tl*16 + qd4*4);
            #pragma unroll
            for (int qt = 0; qt < 2; ++qt)
                #pragma unroll
                for (int i = 0; i < 4; ++i) {
                    float cs = acc[qt][i] * vq[qt] * iv4[i];
                    cs = (cs > 0.f) ? cs : 2.0f;   // masked/zero -> all kernels ~0
                    float t0 = cs - 1.0f;
                    float u  = cs - 0.9f;
                    float s0 = __expf(-500000.f * t0 * t0);
                    float e  = __expf(-50.f * u * u);
                    float rr = __expf(-20.f * cs);
                    pkl[qt][0] += s0;
                    pkl[qt][1] += e;
                    #pragma unroll
                    for (int kk = 0; kk < 9; ++kk) {
                        e = e * rr * CkR[kk];
                        pkl[qt][2 + kk] += e;
                    }
                }
            #pragma unroll
            for (int qt = 0; qt < 2; ++qt)
                #pragma unroll
                for (int k = 0; k < 11; ++k) {
                    float v = pkl[qt][k];
                    v += __shfl_xor(v, 16);
                    v += __shfl_xor(v, 32);
                    if (qd4 == 0) atomicAdd(&pk[(qi*32 + qt*16 + l15)*12 + k], v);
                }
        }
    }
    __syncthreads();

    // flush block partial to global accumulator
    float* dst = pkg + (b*3 + dj)*1152;
    #pragma unroll
    for (int i = 0; i < 5; ++i) {
        int idx = tid + i*256;
        if (idx < 1152) atomicAdd(&dst[idx], pk[idx]);
    }
}

// ---------------------------------------------------------------------------
// Final, R6: per-b block. Parallel log tail (99 (dji,k) pairs x 8 q-groups,
// shfl reduce) + dense dot via LDS tree. Replaces pool tail + old final.
// ---------------------------------------------------------------------------
__global__ __launch_bounds__(256, 2) void final_kernel(
    const float* __restrict__ pkg, const int* __restrict__ qtok,
    const float* __restrict__ dw, float* __restrict__ out)
{
    __shared__ float qm[96];
    __shared__ float fl[99];
    __shared__ float red[256];

    const int tid = threadIdx.x;
    const int b = blockIdx.x;

    if (tid < 96) {
        int qr = tid & 31;
        qm[tid] = ((qr < Qn) && (qtok[b*Qn + qr] > 0)) ? 1.f : 0.f;
    }
    __syncthreads();

    #pragma unroll
    for (int s = 0; s < 4; ++s) {
        int slot = tid + s*256;
        if (slot < 792) {
            int pair = slot >> 3, qc = slot & 7;
            int dji = pair / 11, k = pair - dji*11;
            int qi = dji / 3, dj = dji - qi*3;
            const float* pp = pkg + (b*3 + dj)*1152;
            float ps = 0.f;
            #pragma unroll
            for (int i = 0; i < 4; ++i) {
                int q = qc*4 + i;                   // 0..31 (qm=0 for q>=30)
                ps += qm[qi*32 + q] * 0.01f * __logf(fmaxf(pp[(qi*32 + q)*12 + k], 1e-10f));
            }
            ps += __shfl_xor(ps, 1);
            ps += __shfl_xor(ps, 2);
            ps += __shfl_xor(ps, 4);
            if (qc == 0) fl[pair] = ps;
        }
    }
    __syncthreads();

    red[tid] = (tid < 99) ? fl[tid] * dw[tid] : 0.f;
    __syncthreads();
    #pragma unroll
    for (int s = 128; s > 0; s >>= 1) {
        if (tid < s) red[tid] += red[tid + s];
        __syncthreads();
    }
    if (tid == 0) out[b] = red[0];
}

extern "C" void kernel_launch(void* const* d_in, const int* in_sizes, int n_in,
                              void* d_out, int out_size, void* d_ws, size_t ws_size,
                              hipStream_t stream) {
    const int*   qtok = (const int*)d_in[0];
    const int*   dtok = (const int*)d_in[1];
    const float* emb  = (const float*)d_in[2];
    const float* w1   = (const float*)d_in[3];
    const float* w2   = (const float*)d_in[4];
    const float* w3   = (const float*)d_in[5];
    const float* b1   = (const float*)d_in[6];
    const float* b2   = (const float*)d_in[7];
    const float* b3   = (const float*)d_in[8];
    const float* dw   = (const float*)d_in[9];
    float* out = (float*)d_out;

    char* w = (char*)d_ws;
    u16*   Wt3   = (u16*)w;                      // 491,520 B
    u16*   qg    = (u16*)(w + 491520);           // 3*128*32*128*2  = 3,145,728
    u16*   dgm   = (u16*)(w + 3637248);          // 3*128*208*128*2 = 20,447,232
    float* invq_ = (float*)(w + 24084480);       // 49,152
    float* invd_ = (float*)(w + 24133632);       // 319,488
    float* pkg   = (float*)(w + 24453120);       // 128*3*96*12*4 = 1,769,472
                                                 // total 26,222,592

    prep_kernel<<<dim3(15, B_), 256, 0, stream>>>(w1, w2, w3, Wt3, pkg);

    conv_kernel<<<dim3(512), 512, 0, stream>>>(
        qtok, dtok, emb, Wt3, b1, b2, b3, qg, dgm, invq_, invd_);

    pool_kernel<<<dim3(3, B_, 4), 256, 0, stream>>>(qg, dgm, invq_, invd_, qtok, dtok, pkg);

    final_kernel<<<B_, 256, 0, stream>>>(pkg, qtok, dw, out);
}